// Round 2
// baseline (1087.878 us; speedup 1.0000x reference)
//
#include <hip/hip_runtime.h>
#include <stdint.h>

#define NB 16
#define TQ 1369
#define TS 5476
#define DD 768

#define BM 128
#define BN 128
#define KB 24          // k-blocks of 32 (768/32)
#define RBQ 11         // query row-blocks per n  (11*128 = 1408)
#define RBS 43         // support row-blocks per n (43*128 = 5504)
#define QPAD 1408
#define SPAD 5504
#define SC 8           // support chunks (43 tiles -> 6,6,6,5,5,5,5,5)
#define CAP 16         // candidate slots per row per chunk
#define EPS_SEL 2.5e-3f

typedef float f32x4 __attribute__((ext_vector_type(4)));
typedef short short8 __attribute__((ext_vector_type(8)));
typedef unsigned short ushort;

// ---------- helpers ----------

__device__ inline float waveReduceSum(float v) {
    #pragma unroll
    for (int m = 32; m >= 1; m >>= 1) v += __shfl_xor(v, m);
    return v;
}

// fp32 -> bf16 with round-to-nearest-even, returns low 16 bits
__device__ inline unsigned bf16rne(float x) {
    unsigned u = __float_as_uint(x);
    return (u + 0x7FFFu + ((u >> 16) & 1u)) >> 16;
}
__device__ inline unsigned pack2(float lo, float hi) {
    return bf16rne(lo) | (bf16rne(hi) << 16);
}

__device__ inline f32x4 mfma16(short8 a, short8 b, f32x4 c) {
    return __builtin_amdgcn_mfma_f32_16x16x32_bf16(a, b, c, 0, 0, 0);
}

// async 16B/lane global->LDS DMA (wave-uniform LDS base + lane*16)
__device__ inline void async16(const void* g, void* l) {
    __builtin_amdgcn_global_load_lds(
        (const __attribute__((address_space(1))) unsigned*)g,
        (__attribute__((address_space(3))) unsigned*)l, 16, 0, 0);
}

// monotone float<->uint mapping so unsigned atomicMax == float max
__device__ inline unsigned fsort(float f) {
    unsigned u = __float_as_uint(f);
    return (u & 0x80000000u) ? ~u : (u | 0x80000000u);
}
__device__ inline float funsort(unsigned u) {
    return __uint_as_float((u & 0x80000000u) ? (u & 0x7FFFFFFFu) : ~u);
}

// ---------- kernel 1: cls = l2norm(mean over shots) ----------

__global__ __launch_bounds__(256) void cls_kernel(const float* __restrict__ xc,
                                                  float* __restrict__ cls) {
    int n = blockIdx.x, tid = threadIdx.x;
    const float* base = xc + (size_t)n * 4 * DD;
    float v[3]; float ss = 0.f;
    #pragma unroll
    for (int i = 0; i < 3; i++) {
        int e = tid + i * 256;
        float a = base[e] + base[DD + e] + base[2 * DD + e] + base[3 * DD + e];
        v[i] = a * 0.25f; ss += v[i] * v[i];
    }
    ss = waveReduceSum(ss);
    __shared__ float red[4]; __shared__ float rn;
    if ((tid & 63) == 0) red[tid >> 6] = ss;
    __syncthreads();
    if (tid == 0) {
        float t = red[0] + red[1] + red[2] + red[3];
        rn = 1.0f / fmaxf(sqrtf(t), 1e-12f);
    }
    __syncthreads();
    float r = rn;
    #pragma unroll
    for (int i = 0; i < 3; i++) cls[(size_t)n * DD + tid + i * 256] = v[i] * r;
}

// ---------- kernel 2: normalized bf16 (RNE), dense tiled [n][rb][kb][g][128][8] ----------
// tile = 4096 ushorts (8192 B): 4 kgroups x 128 rows x 8 elems -> 16-lane-contiguous frag reads

__global__ __launch_bounds__(256) void split_kernel(const float* __restrict__ Q,
                                                    const float* __restrict__ S,
                                                    ushort* __restrict__ Qh,
                                                    ushort* __restrict__ Sh,
                                                    float* __restrict__ rq,
                                                    float* __restrict__ rs) {
    int wid = (int)((blockIdx.x * 256u + threadIdx.x) >> 6);
    int lane = threadIdx.x & 63;
    bool isQ = wid < NB * QPAD;
    int n, row, nreal;
    if (isQ) { n = wid / QPAD; row = wid % QPAD; nreal = TQ; }
    else     { int w2 = wid - NB * QPAD; n = w2 / SPAD; row = w2 % SPAD; nreal = TS; }
    int rb = row >> 7, p = row & 127;
    size_t tbase = isQ ? (size_t)(n * RBQ + rb) * KB * 4096
                       : (size_t)(n * RBS + rb) * KB * 4096;
    ushort* outp = (isQ ? Qh : Sh) + tbase;

    if (row >= nreal) {                 // zero pad rows (ws is poisoned 0xAA)
        uint4 z = {0u, 0u, 0u, 0u};
        for (int t = lane; t < 96; t += 64) {
            int kb = t >> 2, g = t & 3;
            *(uint4*)(outp + (size_t)kb * 4096 + g * 1024 + p * 8) = z;
        }
        return;
    }

    const float* src = isQ ? Q + ((size_t)n * TQ + row) * DD
                           : S + ((size_t)n * TS + row) * DD;
    float4 x[3]; float ss = 0.f;
    #pragma unroll
    for (int i = 0; i < 3; i++) {
        x[i] = ((const float4*)src)[lane + i * 64];
        ss += x[i].x * x[i].x + x[i].y * x[i].y + x[i].z * x[i].z + x[i].w * x[i].w;
    }
    ss = waveReduceSum(ss);
    float r = 1.0f / fmaxf(sqrtf(ss), 1e-12f);
    if (lane == 0) {
        if (isQ) rq[(size_t)n * TQ + row] = r; else rs[(size_t)n * TS + row] = r;
    }
    #pragma unroll
    for (int i = 0; i < 3; i++) {
        float ax = x[i].x * r, ay = x[i].y * r, az = x[i].z * r, aw = x[i].w * r;
        int k0 = lane * 4 + i * 256;
        int kb = k0 >> 5;
        int g  = (k0 >> 3) & 3;
        int sub = k0 & 7;               // 0 or 4
        uint2 hv;
        hv.x = pack2(ax, ay);
        hv.y = pack2(az, aw);
        *(uint2*)(outp + (size_t)kb * 4096 + g * 1024 + p * 8 + sub) = hv;
    }
}

// ---------- kernel 3: fused bf16 GEMM + per-row running-max select ----------
// grid (RBQ, SC, NB). Each block: 128 q-rows x one support chunk (5-6 tiles of 128),
// serial K-loop per tile, epilogue folds tile dots into per-row running max +
// candidate list (superset of all dots >= finalmax - EPS: runmax only grows, so
// d >= finalmax-EPS implies d >= runmax_at_push-EPS). No dist matrix in HBM.

__global__ __launch_bounds__(256, 4) void gemm_sel(const ushort* __restrict__ Qh,
                                                   const ushort* __restrict__ Sh,
                                                   float* __restrict__ cmax,
                                                   int* __restrict__ ccnt,
                                                   uint2* __restrict__ cpair) {
    __shared__ __align__(16) ushort As[4096];   // 8 KB
    __shared__ __align__(16) ushort Bs[4096];   // 8 KB
    __shared__ unsigned runmaxU[128];           // sortable-uint running max per row
    __shared__ int cnt[128];
    __shared__ uint2 cand[128][CAP];            // 16 KB

    int tid = threadIdx.x, w = tid >> 6, lane = tid & 63;
    int bx = blockIdx.x, ch = blockIdx.y, n = blockIdx.z;
    int wm = w & 1, wn = w >> 1, g4 = lane >> 4, c16 = lane & 15;

    if (tid < 128) { runmaxU[tid] = 0u; cnt[tid] = 0; }   // fsort(any real) > 0
    __syncthreads();

    // waves 0,1 stage A halves; 2,3 stage B halves (same as old gemm1)
    const char* gA = (const char*)(Qh + (size_t)(n * RBQ + bx) * KB * 4096)
                     + wm * 4096 + lane * 16;
    char* lbase = (char*)((w < 2) ? As : Bs) + wm * 4096;
    int aoff = g4 * 1024 + wm * 512 + c16 * 8;
    int boff = g4 * 1024 + wn * 512 + c16 * 8;

    // chunk ch covers support tiles [t0, t1): sizes 6,6,6,5,5,5,5,5 (sum 43)
    int t0 = ch * 5 + min(ch, 3);
    int t1 = t0 + (ch < 3 ? 6 : 5);

    for (int by = t0; by < t1; by++) {
        const char* gsrc = (w < 2) ? gA
            : (const char*)(Sh + (size_t)(n * RBS + by) * KB * 4096) + wm * 4096 + lane * 16;

        f32x4 acc[4][4] = {};
        for (int kb = 0; kb < KB; kb++) {
            #pragma unroll
            for (int j = 0; j < 4; j++)
                async16(gsrc + (size_t)kb * 8192 + j * 1024, lbase + j * 1024);
            __syncthreads();

            short8 ah[4], bh[4];
            #pragma unroll
            for (int i = 0; i < 4; i++) {
                ah[i] = *(const short8*)&As[aoff + i * 128];
                bh[i] = *(const short8*)&Bs[boff + i * 128];
            }
            #pragma unroll
            for (int mi = 0; mi < 4; mi++)
                #pragma unroll
                for (int ni = 0; ni < 4; ni++)
                    acc[mi][ni] = mfma16(ah[mi], bh[ni], acc[mi][ni]);
            __syncthreads();
        }

        // ---- per-tile select epilogue ----
        // C layout: row = wm*64 + mi*16 + g4*4 + r, col = by*128 + wn*64 + ni*16 + c16
        int colb = by * 128 + wn * 64 + c16;
        bool edge = (by == RBS - 1);            // only tile containing pad cols

        // 1) per-row max over this wave's 64 cols, merge into running max
        #pragma unroll
        for (int mi = 0; mi < 4; mi++) {
            #pragma unroll
            for (int r = 0; r < 4; r++) {
                float v0 = acc[mi][0][r], v1 = acc[mi][1][r];
                float v2 = acc[mi][2][r], v3 = acc[mi][3][r];
                if (edge) {                     // mask pad cols (zero rows -> dot 0)
                    if (colb +  0 >= TS) v0 = -1e30f;
                    if (colb + 16 >= TS) v1 = -1e30f;
                    if (colb + 32 >= TS) v2 = -1e30f;
                    if (colb + 48 >= TS) v3 = -1e30f;
                }
                float v = fmaxf(fmaxf(v0, v1), fmaxf(v2, v3));
                #pragma unroll
                for (int m = 1; m < 16; m <<= 1) v = fmaxf(v, __shfl_xor(v, m));
                if (c16 == 0) {
                    int row = wm * 64 + mi * 16 + g4 * 4 + r;
                    atomicMax(&runmaxU[row], fsort(v));
                }
            }
        }
        __syncthreads();

        // 2) push candidates within EPS of the running max (conservative superset)
        #pragma unroll
        for (int mi = 0; mi < 4; mi++) {
            #pragma unroll
            for (int r = 0; r < 4; r++) {
                int row = wm * 64 + mi * 16 + g4 * 4 + r;
                float thr = funsort(runmaxU[row]) - EPS_SEL;
                #pragma unroll
                for (int ni = 0; ni < 4; ni++) {
                    float d = acc[mi][ni][r];
                    int col = colb + ni * 16;
                    if (d >= thr && (!edge || col < TS)) {
                        int slot = atomicAdd(&cnt[row], 1);
                        if (slot < CAP) {
                            uint2 pr; pr.x = (unsigned)col; pr.y = __float_as_uint(d);
                            cand[row][slot] = pr;
                        }
                    }
                }
            }
        }
        __syncthreads();   // pushes of tile t complete before tile t+1's merge
    }

    // write per-(row, chunk) record: chunk max + candidate list
    if (tid < 128) {
        size_t rec = ((size_t)n * QPAD + (size_t)bx * 128 + tid) * SC + ch;
        cmax[rec] = funsort(runmaxU[tid]);
        int c = min(cnt[tid], CAP);
        ccnt[rec] = c;
        for (int i = 0; i < c; i++) cpair[rec * CAP + i] = cand[tid][i];
    }
}

// ---------- kernel 4: merge chunk records + exact recheck + head, one wave/query ----------

__global__ __launch_bounds__(256) void merge_head(const float* __restrict__ cmax,
                                                  const int* __restrict__ ccnt,
                                                  const uint2* __restrict__ cpair,
                                                  const float* __restrict__ Q,
                                                  const float* __restrict__ S,
                                                  const float* __restrict__ rq,
                                                  const float* __restrict__ rs,
                                                  const float* __restrict__ cls,
                                                  const float* __restrict__ W,
                                                  const float* __restrict__ bb,
                                                  float* __restrict__ out) {
    int w = threadIdx.x >> 6, lane = threadIdx.x & 63;
    int qi = blockIdx.x * 4 + w;                   // 5476*4 = 21904 exactly
    int n = qi / TQ, qr = qi - n * TQ;
    size_t rec0 = ((size_t)n * QPAD + qr) * SC;

    // final approx max over chunks
    float pm = -1e30f;
    #pragma unroll
    for (int c = 0; c < SC; c++) pm = fmaxf(pm, cmax[rec0 + c]);
    float thr = pm - EPS_SEL;

    const float* qrow = Q + (size_t)qi * DD;
    float4 q4[3];
    #pragma unroll
    for (int i = 0; i < 3; i++) q4[i] = ((const float4*)qrow)[lane + i * 64];
    float rqv = rq[qi];

    float bestd = -1e30f; int bidx = 0x7FFFFFFF;
    float fba = -1e30f;  int fbi = 0;              // fallback: best stored approx

    auto recheck = [&](int sidx) {
        const float* srow = S + ((size_t)n * TS + sidx) * DD;
        float part = 0.f;
        #pragma unroll
        for (int k = 0; k < 3; k++) {
            float4 s4 = ((const float4*)srow)[lane + k * 64];
            part += q4[k].x * s4.x + q4[k].y * s4.y + q4[k].z * s4.z + q4[k].w * s4.w;
        }
        part = waveReduceSum(part);                 // bit-identical on all lanes
        float dot = part * rqv * rs[(size_t)n * TS + sidx];
        if (dot > bestd || (dot == bestd && sidx < bidx)) { bestd = dot; bidx = sidx; }
    };

    for (int c = 0; c < SC; c++) {
        int cn = ccnt[rec0 + c];                    // uniform across wave (same addr)
        for (int i = 0; i < cn; i++) {
            uint2 pr = cpair[(rec0 + c) * CAP + i];
            int sidx = (int)pr.x;
            float ad = __uint_as_float(pr.y);
            if (ad > fba) { fba = ad; fbi = sidx; }
            if (ad >= thr) recheck(sidx);           // exact fp32 verify
        }
    }
    if (bidx == 0x7FFFFFFF) recheck(fbi);           // safety net (CAP overflow path)
    float dmin = 1.0f - bestd;

    // head: sigmoid(q_n·W0 + s_n·W1 + cls·W2 + b)
    const float* srow = S + ((size_t)n * TS + bidx) * DD;
    const float* clsr = cls + (size_t)n * DD;
    float rsv = rs[(size_t)n * TS + bidx];
    float aq = 0.f, as_ = 0.f, ac = 0.f;
    #pragma unroll
    for (int i = 0; i < 3; i++) {
        float4 s4 = ((const float4*)srow)[lane + i * 64];
        float4 c4 = ((const float4*)clsr)[lane + i * 64];
        float4 w0 = ((const float4*)W)[lane + i * 64];
        float4 w1 = ((const float4*)(W + DD))[lane + i * 64];
        float4 w2 = ((const float4*)(W + 2 * DD))[lane + i * 64];
        aq += q4[i].x * w0.x + q4[i].y * w0.y + q4[i].z * w0.z + q4[i].w * w0.w;
        as_ += s4.x * w1.x + s4.y * w1.y + s4.z * w1.z + s4.w * w1.w;
        ac += c4.x * w2.x + c4.y * w2.y + c4.z * w2.z + c4.w * w2.w;
    }
    float tot = waveReduceSum(aq * rqv + as_ * rsv + ac);
    if (lane == 0) {
        float logit = tot + bb[0];
        float pred = 1.0f / (1.0f + expf(-logit));
        out[qi] = pred * dmin;
        out[NB * TQ + qi] = pred;
    }
}

// ---------- launch ----------

extern "C" void kernel_launch(void* const* d_in, const int* in_sizes, int n_in,
                              void* d_out, int out_size, void* d_ws, size_t ws_size,
                              hipStream_t stream) {
    const float* Q  = (const float*)d_in[0];
    const float* S  = (const float*)d_in[1];
    const float* XC = (const float*)d_in[2];
    const float* W  = (const float*)d_in[3];
    const float* B  = (const float*)d_in[4];
    (void)in_sizes; (void)n_in; (void)out_size;

    char* ws = (char*)d_ws;
    ushort* Qh    = (ushort*)ws;                          //  34,603,008 B
    ushort* Sh    = (ushort*)(ws + 34603008ull);          // 135,266,304 B -> 169,869,312
    float*  rq    = (float*)(ws + 169869312ull);          //      87,616 B -> 169,956,928
    float*  rs    = (float*)(ws + 169956928ull);          //     350,464 B -> 170,307,392
    float*  cls   = (float*)(ws + 170307392ull);          //      49,152 B -> 170,356,544
    float*  cmax  = (float*)(ws + 170356544ull);          //     720,896 B -> 171,077,440
    int*    ccnt  = (int*)(ws + 171077440ull);            //     720,896 B -> 171,798,336
    uint2*  cpair = (uint2*)(ws + 171798336ull);          //  23,068,672 B -> 194,867,008
    // total 194,867,008 B (old layout proved ws >= 417 MB, so this fits)
    if (ws_size < 194867008ull) return;

    cls_kernel<<<NB, 256, 0, stream>>>(XC, cls);

    // 16*1408 + 16*5504 = 110,592 waves / 4 per block
    split_kernel<<<27648, 256, 0, stream>>>(Q, S, Qh, Sh, rq, rs);

    dim3 grid(RBQ, SC, NB);                               // (11, 8, 16) = 1408 blocks
    gemm_sel<<<grid, 256, 0, stream>>>(Qh, Sh, cmax, ccnt, cpair);

    merge_head<<<(NB * TQ) / 4, 256, 0, stream>>>(cmax, ccnt, cpair, Q, S, rq, rs,
                                                  cls, W, B, (float*)d_out);
}

// Round 3
// 812.574 us; speedup vs baseline: 1.3388x; 1.3388x over previous
//
#include <hip/hip_runtime.h>
#include <stdint.h>

#define NB 16
#define TQ 1369
#define TS 5476
#define DD 768

#define BM 128
#define BN 128
#define KB 24          // k-blocks of 32 (768/32)
#define RBQ 11         // query row-blocks per n  (11*128 = 1408)
#define RBS 43         // support row-blocks per n (43*128 = 5504)
#define QPAD 1408
#define SPAD 5504
#define NROWS (NB * QPAD)        // 22528 padded query rows total
#define CAP 8                    // candidate slots per (row, tile) record
#define EPS_SEL 2.5e-3f

typedef float f32x4 __attribute__((ext_vector_type(4)));
typedef short short8 __attribute__((ext_vector_type(8)));
typedef unsigned short ushort;
typedef unsigned long long ull;

// ---------- helpers ----------

__device__ inline float waveReduceSum(float v) {
    #pragma unroll
    for (int m = 32; m >= 1; m >>= 1) v += __shfl_xor(v, m);
    return v;
}

// fp32 -> bf16 with round-to-nearest-even, returns low 16 bits
__device__ inline unsigned bf16rne(float x) {
    unsigned u = __float_as_uint(x);
    return (u + 0x7FFFu + ((u >> 16) & 1u)) >> 16;
}
__device__ inline unsigned pack2(float lo, float hi) {
    return bf16rne(lo) | (bf16rne(hi) << 16);
}

__device__ inline f32x4 mfma16(short8 a, short8 b, f32x4 c) {
    return __builtin_amdgcn_mfma_f32_16x16x32_bf16(a, b, c, 0, 0, 0);
}

// async 16B/lane global->LDS DMA (wave-uniform LDS base + lane*16)
__device__ inline void async16(const void* g, void* l) {
    __builtin_amdgcn_global_load_lds(
        (const __attribute__((address_space(1))) unsigned*)g,
        (__attribute__((address_space(3))) unsigned*)l, 16, 0, 0);
}

// monotone float<->uint mapping so unsigned max == float max
__device__ inline unsigned fsort(float f) {
    unsigned u = __float_as_uint(f);
    return (u & 0x80000000u) ? ~u : (u | 0x80000000u);
}
__device__ inline float funsort(unsigned u) {
    return __uint_as_float((u & 0x80000000u) ? (u & 0x7FFFFFFFu) : ~u);
}

// ---------- kernel 1: cls = l2norm(mean over shots) ----------

__global__ __launch_bounds__(256) void cls_kernel(const float* __restrict__ xc,
                                                  float* __restrict__ cls) {
    int n = blockIdx.x, tid = threadIdx.x;
    const float* base = xc + (size_t)n * 4 * DD;
    float v[3]; float ss = 0.f;
    #pragma unroll
    for (int i = 0; i < 3; i++) {
        int e = tid + i * 256;
        float a = base[e] + base[DD + e] + base[2 * DD + e] + base[3 * DD + e];
        v[i] = a * 0.25f; ss += v[i] * v[i];
    }
    ss = waveReduceSum(ss);
    __shared__ float red[4]; __shared__ float rn;
    if ((tid & 63) == 0) red[tid >> 6] = ss;
    __syncthreads();
    if (tid == 0) {
        float t = red[0] + red[1] + red[2] + red[3];
        rn = 1.0f / fmaxf(sqrtf(t), 1e-12f);
    }
    __syncthreads();
    float r = rn;
    #pragma unroll
    for (int i = 0; i < 3; i++) cls[(size_t)n * DD + tid + i * 256] = v[i] * r;
}

// ---------- kernel 2: normalized bf16 (RNE), dense tiled [n][rb][kb][g][128][8] ----------

__global__ __launch_bounds__(256) void split_kernel(const float* __restrict__ Q,
                                                    const float* __restrict__ S,
                                                    ushort* __restrict__ Qh,
                                                    ushort* __restrict__ Sh,
                                                    float* __restrict__ rq,
                                                    float* __restrict__ rs) {
    int wid = (int)((blockIdx.x * 256u + threadIdx.x) >> 6);
    int lane = threadIdx.x & 63;
    bool isQ = wid < NB * QPAD;
    int n, row, nreal;
    if (isQ) { n = wid / QPAD; row = wid % QPAD; nreal = TQ; }
    else     { int w2 = wid - NB * QPAD; n = w2 / SPAD; row = w2 % SPAD; nreal = TS; }
    int rb = row >> 7, p = row & 127;
    size_t tbase = isQ ? (size_t)(n * RBQ + rb) * KB * 4096
                       : (size_t)(n * RBS + rb) * KB * 4096;
    ushort* outp = (isQ ? Qh : Sh) + tbase;

    if (row >= nreal) {                 // zero pad rows (ws is poisoned 0xAA)
        uint4 z = {0u, 0u, 0u, 0u};
        for (int t = lane; t < 96; t += 64) {
            int kb = t >> 2, g = t & 3;
            *(uint4*)(outp + (size_t)kb * 4096 + g * 1024 + p * 8) = z;
        }
        return;
    }

    const float* src = isQ ? Q + ((size_t)n * TQ + row) * DD
                           : S + ((size_t)n * TS + row) * DD;
    float4 x[3]; float ss = 0.f;
    #pragma unroll
    for (int i = 0; i < 3; i++) {
        x[i] = ((const float4*)src)[lane + i * 64];
        ss += x[i].x * x[i].x + x[i].y * x[i].y + x[i].z * x[i].z + x[i].w * x[i].w;
    }
    ss = waveReduceSum(ss);
    float r = 1.0f / fmaxf(sqrtf(ss), 1e-12f);
    if (lane == 0) {
        if (isQ) rq[(size_t)n * TQ + row] = r; else rs[(size_t)n * TS + row] = r;
    }
    #pragma unroll
    for (int i = 0; i < 3; i++) {
        float ax = x[i].x * r, ay = x[i].y * r, az = x[i].z * r, aw = x[i].w * r;
        int k0 = lane * 4 + i * 256;
        int kb = k0 >> 5;
        int g  = (k0 >> 3) & 3;
        int sub = k0 & 7;               // 0 or 4
        uint2 hv;
        hv.x = pack2(ax, ay);
        hv.y = pack2(az, aw);
        *(uint2*)(outp + (size_t)kb * 4096 + g * 1024 + p * 8 + sub) = hv;
    }
}

// ---------- kernel 3: bf16 GEMM tile + per-(row,tile) max/argmax/candidate record ----------
// grid (RBQ, RBS, NB) — one 128x128 tile per block (round-0 geometry: proven 738 MB
// fetch via L2/LLC sharing among co-resident same-by blocks). Epilogue: per row,
// tile max + argmax (16-lane shfl reduce w/ index), push others >= tilemax - EPS.
// tilemax <= globalmax, so records are a superset of {d >= globalmax - EPS}.
// Record: hdr[by*NROWS + rowg] = (max, cnt); cpair[rec*CAP + 0] = argmax (always).

__global__ __launch_bounds__(256, 4) void gemm_sel(const ushort* __restrict__ Qh,
                                                   const ushort* __restrict__ Sh,
                                                   float2* __restrict__ hdr,
                                                   uint2* __restrict__ cpair) {
    __shared__ __align__(16) ushort As[4096];   // 8 KB
    __shared__ __align__(16) ushort Bs[4096];   // 8 KB
    __shared__ ull key[128];                    // packed (fsort(max)<<32 | 8191-col)
    __shared__ int cnt[128];
    __shared__ uint2 cand[128][CAP];            // slots 1..CAP-1 used (0 = argmax)

    int tid = threadIdx.x, w = tid >> 6, lane = tid & 63;
    int bx = blockIdx.x, by = blockIdx.y, n = blockIdx.z;
    int wm = w & 1, wn = w >> 1, g4 = lane >> 4, c16 = lane & 15;

    if (tid < 128) { key[tid] = 0ull; cnt[tid] = 1; }   // slot 0 reserved for argmax
    __syncthreads();

    // waves 0,1 stage A halves; 2,3 stage B halves (identical to round-0 gemm1)
    const char* gsrc = (const char*)((w < 2)
        ? (Qh + (size_t)(n * RBQ + bx) * KB * 4096)
        : (Sh + (size_t)(n * RBS + by) * KB * 4096)) + wm * 4096 + lane * 16;
    char* lbase = (char*)((w < 2) ? As : Bs) + wm * 4096;

    f32x4 acc[4][4] = {};
    int aoff = g4 * 1024 + wm * 512 + c16 * 8;
    int boff = g4 * 1024 + wn * 512 + c16 * 8;

    for (int kb = 0; kb < KB; kb++) {
        #pragma unroll
        for (int j = 0; j < 4; j++)
            async16(gsrc + (size_t)kb * 8192 + j * 1024, lbase + j * 1024);
        __syncthreads();

        short8 ah[4], bh[4];
        #pragma unroll
        for (int i = 0; i < 4; i++) {
            ah[i] = *(const short8*)&As[aoff + i * 128];
            bh[i] = *(const short8*)&Bs[boff + i * 128];
        }
        #pragma unroll
        for (int mi = 0; mi < 4; mi++)
            #pragma unroll
            for (int ni = 0; ni < 4; ni++)
                acc[mi][ni] = mfma16(ah[mi], bh[ni], acc[mi][ni]);
        __syncthreads();
    }

    // ---- epilogue: per-row tile max + argmax ----
    // C layout: row = wm*64 + mi*16 + g4*4 + r, col = by*128 + wn*64 + ni*16 + c16
    int colb = by * 128 + wn * 64 + c16;
    bool edge = (by == RBS - 1);            // only tile containing pad cols

    #pragma unroll
    for (int mi = 0; mi < 4; mi++) {
        #pragma unroll
        for (int r = 0; r < 4; r++) {
            float v = -1e30f; int c = 0;
            #pragma unroll
            for (int ni = 0; ni < 4; ni++) {
                float d = acc[mi][ni][r];
                int col = colb + ni * 16;
                if ((!edge || col < TS) && d > v) { v = d; c = col; }
            }
            #pragma unroll
            for (int m = 1; m < 16; m <<= 1) {   // xor<16 stays within 16-lane group
                float ov = __shfl_xor(v, m);
                int   oc = __shfl_xor(c, m);
                if (ov > v || (ov == v && oc < c)) { v = ov; c = oc; }
            }
            if (c16 == 0) {
                int row = wm * 64 + mi * 16 + g4 * 4 + r;
                ull k = ((ull)fsort(v) << 32) | (unsigned)(8191 - c);
                atomicMax(&key[row], k);
            }
        }
    }
    __syncthreads();

    // ---- push other candidates >= tilemax - EPS ----
    #pragma unroll
    for (int mi = 0; mi < 4; mi++) {
        #pragma unroll
        for (int r = 0; r < 4; r++) {
            int row = wm * 64 + mi * 16 + g4 * 4 + r;
            ull k = key[row];
            float mx = funsort((unsigned)(k >> 32));
            int amc = 8191 - (int)(k & 0xFFFFFFFFull);
            float thr = mx - EPS_SEL;
            #pragma unroll
            for (int ni = 0; ni < 4; ni++) {
                float d = acc[mi][ni][r];
                int col = colb + ni * 16;
                if ((!edge || col < TS) && d >= thr && col != amc) {
                    int slot = atomicAdd(&cnt[row], 1);
                    if (slot < CAP) {
                        uint2 pr; pr.x = (unsigned)col; pr.y = __float_as_uint(d);
                        cand[row][slot] = pr;
                    }
                }
            }
        }
    }
    __syncthreads();

    // ---- write record (coalesced: consecutive tid -> consecutive rows) ----
    if (tid < 128) {
        ull k = key[tid];
        float mx = funsort((unsigned)(k >> 32));
        int amc = 8191 - (int)(k & 0xFFFFFFFFull);
        int cn = min(cnt[tid], CAP);
        size_t rowg = (size_t)n * QPAD + (size_t)bx * 128 + tid;
        size_t rec = (size_t)by * NROWS + rowg;
        hdr[rec] = make_float2(mx, __int_as_float(cn));
        uint2 a0; a0.x = (unsigned)amc; a0.y = __float_as_uint(mx);
        cpair[rec * CAP] = a0;
        for (int i = 1; i < cn; i++) cpair[rec * CAP + i] = cand[tid][i];
    }
}

// ---------- kernel 4: merge tile records + exact recheck + head, one wave/query ----------

__global__ __launch_bounds__(256) void merge_head(const float2* __restrict__ hdr,
                                                  const uint2* __restrict__ cpair,
                                                  const float* __restrict__ Q,
                                                  const float* __restrict__ S,
                                                  const float* __restrict__ rq,
                                                  const float* __restrict__ rs,
                                                  const float* __restrict__ cls,
                                                  const float* __restrict__ W,
                                                  const float* __restrict__ bb,
                                                  float* __restrict__ out) {
    int w = threadIdx.x >> 6, lane = threadIdx.x & 63;
    int qi = blockIdx.x * 4 + w;                   // 5476*4 = 21904 exactly
    int n = qi / TQ, qr = qi - n * TQ;
    size_t rowg = (size_t)n * QPAD + qr;

    // lane l holds tile l's record header (l < RBS)
    float mx_l = -1e30f; int cnt_l = 0;
    if (lane < RBS) {
        float2 h = hdr[(size_t)lane * NROWS + rowg];
        mx_l = h.x; cnt_l = __float_as_int(h.y);
    }
    float gm = mx_l;
    #pragma unroll
    for (int m = 32; m >= 1; m >>= 1) gm = fmaxf(gm, __shfl_xor(gm, m));
    float thr = gm - EPS_SEL;

    const float* qrow = Q + (size_t)qi * DD;
    float4 q4[3];
    #pragma unroll
    for (int i = 0; i < 3; i++) q4[i] = ((const float4*)qrow)[lane + i * 64];
    float rqv = rq[qi];

    float bestd = -1e30f; int bidx = 0x7FFFFFFF;

    auto recheck = [&](int sidx) {
        const float* srow = S + ((size_t)n * TS + sidx) * DD;
        float part = 0.f;
        #pragma unroll
        for (int k = 0; k < 3; k++) {
            float4 s4 = ((const float4*)srow)[lane + k * 64];
            part += q4[k].x * s4.x + q4[k].y * s4.y + q4[k].z * s4.z + q4[k].w * s4.w;
        }
        part = waveReduceSum(part);                 // bit-identical on all lanes
        float dot = part * rqv * rs[(size_t)n * TS + sidx];
        if (dot > bestd || (dot == bestd && sidx < bidx)) { bestd = dot; bidx = sidx; }
    };

    // only tiles whose max is within EPS of gm can hold candidates; usually 1-2
    ull ball = __ballot(lane < RBS && mx_l >= thr);
    while (ball) {
        int src = __ffsll((long long)ball) - 1;
        ball &= ball - 1;
        int cn = __shfl(cnt_l, src);
        size_t rec = (size_t)src * NROWS + rowg;
        for (int i = 0; i < cn; i++) {
            uint2 pr = cpair[rec * CAP + i];        // wave-uniform -> broadcast load
            float ad = __uint_as_float(pr.y);
            if (ad >= thr) recheck((int)pr.x);      // exact fp32 verify
        }
    }
    if (bidx == 0x7FFFFFFF) bidx = 0;               // unreachable guard (gm rec slot 0)
    float dmin = 1.0f - bestd;

    // head: sigmoid(q_n·W0 + s_n·W1 + cls·W2 + b)
    const float* srow = S + ((size_t)n * TS + bidx) * DD;
    const float* clsr = cls + (size_t)n * DD;
    float rsv = rs[(size_t)n * TS + bidx];
    float aq = 0.f, as_ = 0.f, ac = 0.f;
    #pragma unroll
    for (int i = 0; i < 3; i++) {
        float4 s4 = ((const float4*)srow)[lane + i * 64];
        float4 c4 = ((const float4*)clsr)[lane + i * 64];
        float4 w0 = ((const float4*)W)[lane + i * 64];
        float4 w1 = ((const float4*)(W + DD))[lane + i * 64];
        float4 w2 = ((const float4*)(W + 2 * DD))[lane + i * 64];
        aq += q4[i].x * w0.x + q4[i].y * w0.y + q4[i].z * w0.z + q4[i].w * w0.w;
        as_ += s4.x * w1.x + s4.y * w1.y + s4.z * w1.z + s4.w * w1.w;
        ac += c4.x * w2.x + c4.y * w2.y + c4.z * w2.z + c4.w * w2.w;
    }
    float tot = waveReduceSum(aq * rqv + as_ * rsv + ac);
    if (lane == 0) {
        float logit = tot + bb[0];
        float pred = 1.0f / (1.0f + expf(-logit));
        out[qi] = pred * dmin;
        out[NB * TQ + qi] = pred;
    }
}

// ---------- launch ----------

extern "C" void kernel_launch(void* const* d_in, const int* in_sizes, int n_in,
                              void* d_out, int out_size, void* d_ws, size_t ws_size,
                              hipStream_t stream) {
    const float* Q  = (const float*)d_in[0];
    const float* S  = (const float*)d_in[1];
    const float* XC = (const float*)d_in[2];
    const float* W  = (const float*)d_in[3];
    const float* B  = (const float*)d_in[4];
    (void)in_sizes; (void)n_in; (void)out_size;

    char* ws = (char*)d_ws;
    ushort* Qh    = (ushort*)ws;                          //  34,603,008 B
    ushort* Sh    = (ushort*)(ws + 34603008ull);          // 135,266,304 B -> 169,869,312
    float*  rq    = (float*)(ws + 169869312ull);          //      87,616 B -> 169,956,928
    float*  rs    = (float*)(ws + 169956928ull);          //     350,464 B -> 170,307,392
    float*  cls   = (float*)(ws + 170307392ull);          //      49,152 B -> 170,356,544
    float2* hdr   = (float2*)(ws + 170356544ull);         //   7,749,632 B -> 178,106,176
    uint2*  cpair = (uint2*)(ws + 178106176ull);          //  61,997,056 B -> 240,103,232
    // total 240,103,232 B (ws proven >= 417 MB previously)
    if (ws_size < 240103232ull) return;

    cls_kernel<<<NB, 256, 0, stream>>>(XC, cls);

    // 16*1408 + 16*5504 = 110,592 waves / 4 per block
    split_kernel<<<27648, 256, 0, stream>>>(Q, S, Qh, Sh, rq, rs);

    dim3 grid(RBQ, RBS, NB);                              // (11, 43, 16) = 7568 blocks
    gemm_sel<<<grid, 256, 0, stream>>>(Qh, Sh, hdr, cpair);

    merge_head<<<(NB * TQ) / 4, 256, 0, stream>>>(hdr, cpair, Q, S, rq, rs,
                                                  cls, W, B, (float*)d_out);
}